// Round 5
// baseline (489.630 us; speedup 1.0000x reference)
//
#include <hip/hip_runtime.h>
#include <math.h>

// B=32, S=1024, D=512, F=8, KN=32 knots, H=8, hd=64. M = B*S = 32768 rows.

#define SOFF_AMEAN 0
#define SOFF_ARSTD 512
#define SOFF_OMEAN 1024
#define SOFF_ORSTD 1536
#define SOFF_PMEAN 2048
#define SOFF_PRSTD 2056
#define SOFF_FMIN  2064
#define SOFF_FMAX  2072
#define SOFF_SMEAN 2080
#define SOFF_SRSTD 3104
#define SOFF_G1    4128
#define SOFF_GB    4136
#define SOFF_SGB   4144
#define SOFF_QGB   4145
#define SOFF_G2    4160
#define SOFF_PART  4224

typedef short bf16x8_t __attribute__((ext_vector_type(8)));
typedef float f32x4_t __attribute__((ext_vector_type(4)));
typedef unsigned short us8_t __attribute__((ext_vector_type(8)));

__device__ __forceinline__ unsigned short f2bf(float f) {
  unsigned u = __float_as_uint(f);
  u = (u + 0x7FFFu + ((u >> 16) & 1u)) >> 16;
  return (unsigned short)u;
}
__device__ __forceinline__ float b2f(unsigned short u) {
  return __uint_as_float(((unsigned)u) << 16);
}

// compile-time-only reordering fence around raw s_barrier (NO waitcnt drain)
#define BARR do { asm volatile("" ::: "memory"); __builtin_amdgcn_s_barrier(); asm volatile("" ::: "memory"); } while (0)

#define GLL(gp, lp) __builtin_amdgcn_global_load_lds( \
    (const __attribute__((address_space(1))) void*)(gp), \
    (__attribute__((address_space(3))) void*)(lp), 16, 0, 0)

// ---------------------------------------------------------------- zero scratch
__global__ __launch_bounds__(256) void zero_kernel(float* __restrict__ p) {
  p[blockIdx.x * 256 + threadIdx.x] = 0.f;
}

// ---------------------------------------------------------------- fp32 -> bf16
__global__ __launch_bounds__(256) void cvt8_kernel(const float* __restrict__ src,
                                                   unsigned short* __restrict__ dst) {
  int i = blockIdx.x * 256 + threadIdx.x;
  float4 a = ((const float4*)src)[i * 2];
  float4 b = ((const float4*)src)[i * 2 + 1];
  us8_t o;
  o[0] = f2bf(a.x); o[1] = f2bf(a.y); o[2] = f2bf(a.z); o[3] = f2bf(a.w);
  o[4] = f2bf(b.x); o[5] = f2bf(b.y); o[6] = f2bf(b.z); o[7] = f2bf(b.w);
  *(us8_t*)(dst + (size_t)i * 8) = o;
}

// ------------------------------------------------- bf16 MFMA GEMM  C = A@B^T + bias
// 256x256 tile, BK=64, 8 waves (2Mx4N), 8-phase m201-style schedule:
// 8 K-steps x 4 quadrant-phases. Per phase: {ds_read af quadrant (+bf at q=0),
// stage A-slab of kt+1 (+B-slab of kt+2 / B-slab3 of kt+1), vmcnt(6 counted),
// barrier, setprio(1), 16 MFMA, setprio(0), barrier}. A-slab staged exactly 4
// phases before its read; B-slabs 5-8 ahead (B region free after its phase 0).
// End-of-phase vmcnt(6) retires the pair issued 3 phases earlier => slab at g-4
// guaranteed; tail wait table 5,4,3,2,1,0. LDS 128KB (2 K-step dbuf), XOR
// swizzle chunk^=(row&7) on global source AND ds_read (conflict-free, 2-way max).
template<int NT, bool OUT_BF16, bool STATS>
__global__ __launch_bounds__(512, 2) void gemm256_kernel(
    const unsigned short* __restrict__ A, const unsigned short* __restrict__ B,
    const float* __restrict__ bias, unsigned short* __restrict__ Cb,
    float* __restrict__ Cf, float* __restrict__ gstats, int N) {
  __shared__ unsigned short As[2][256 * 64];
  __shared__ unsigned short Bs[2][256 * 64];
  const int bi = blockIdx.x;
  const int xcd = bi & 7, jb = bi >> 3;          // 128 M-tiles: 16 per XCD
  const int m0 = (xcd * 16 + jb / NT) * 256;
  const int n0 = (jb % NT) * 256;
  const int t = threadIdx.x;
  const int w = t >> 6, lane = t & 63;
  const int wm = w >> 2, wn = w & 3;             // 2 x 4 wave grid

  // staging geometry: slab = 64 rows (32 of each half) x 64 cols = 8KB = 1 round.
  // lane l covers row rs = w*8 + (l>>3) within slab (side adj +96), chunk (l&7)
  // pre-swizzled in global: c_src = (l&7) ^ (l>>3)  [row&7 == l>>3].
  const int rs = w * 8 + (lane >> 3);
  const int rbase = rs + ((rs >> 5) * 96);       // slab-q=0 tile row for this lane
  const unsigned short* gA = A + (size_t)(m0 + rbase) * 512 + (((lane & 7) ^ (lane >> 3)) * 8);
  const unsigned short* gB = B + (size_t)(n0 + rbase) * 512 + (((lane & 7) ^ (lane >> 3)) * 8);
  const int abrow = w * 8 + ((w >> 2) * 96);     // wave-uniform LDS base row (lane 0)

  // fragment read geometry
  const int fr = lane & 15, g = lane >> 4;       // g in 0..3
  const int sw = fr & 7;                         // XOR key (row&7)

  f32x4_t acc[8][4];
#pragma unroll
  for (int i = 0; i < 8; ++i)
#pragma unroll
    for (int jj = 0; jj < 4; ++jj) acc[i][jj] = (f32x4_t){0.f, 0.f, 0.f, 0.f};

  // prologue: A(0) slabs 0-3, B(0) slabs 0-3, B(1) slabs 0-2 (11 loads/wave);
  // vmcnt(3): A(0),B(0) resident, B(1) x3 in flight.
#pragma unroll
  for (int q = 0; q < 4; ++q)
    GLL(gA + (size_t)(q * 32) * 512, &As[0][(q * 32 + abrow) * 64]);
#pragma unroll
  for (int q = 0; q < 4; ++q)
    GLL(gB + (size_t)(q * 32) * 512, &Bs[0][(q * 32 + abrow) * 64]);
#pragma unroll
  for (int q = 0; q < 3; ++q)
    GLL(gB + (size_t)(q * 32) * 512 + 64, &Bs[1][(q * 32 + abrow) * 64]);
  asm volatile("s_waitcnt vmcnt(3)" ::: "memory");
  BARR;

#pragma unroll
  for (int kt = 0; kt < 8; ++kt) {
    const int d = kt & 1;
    const unsigned short* asb = &As[d][0];
    const unsigned short* bsb = &Bs[d][0];
    bf16x8_t bfr[4][2];
#pragma unroll
    for (int q = 0; q < 4; ++q) {
      const int gph = kt * 4 + q;
      // ---- ds reads (current buffer)
      if (q == 0) {
#pragma unroll
        for (int ni = 0; ni < 4; ++ni)
#pragma unroll
          for (int ks = 0; ks < 2; ++ks)
            bfr[ni][ks] = *(const bf16x8_t*)&bsb[(wn * 64 + ni * 16 + fr) * 64
                                                 + (((ks * 4 + g) ^ sw) * 8)];
      }
      bf16x8_t af[2][2];
#pragma unroll
      for (int m2 = 0; m2 < 2; ++m2)
#pragma unroll
        for (int ks = 0; ks < 2; ++ks)
          af[m2][ks] = *(const bf16x8_t*)&asb[(wm * 128 + (q * 2 + m2) * 16 + fr) * 64
                                              + (((ks * 4 + g) ^ sw) * 8)];
      // ---- stages (counted, never drained)
      if (kt < 7)
        GLL(gA + (size_t)(q * 32) * 512 + (size_t)(kt + 1) * 64,
            &As[d ^ 1][(q * 32 + abrow) * 64]);
      if (q == 0) {
        if (kt < 7)
          GLL(gB + (size_t)(3 * 32) * 512 + (size_t)(kt + 1) * 64,
              &Bs[d ^ 1][(3 * 32 + abrow) * 64]);
      } else if (kt < 6) {
        GLL(gB + (size_t)((q - 1) * 32) * 512 + (size_t)(kt + 2) * 64,
            &Bs[d][((q - 1) * 32 + abrow) * 64]);
      }
      // ---- counted wait (tail-aware), publish via barrier
      if (gph <= 24)      asm volatile("s_waitcnt vmcnt(6)" ::: "memory");
      else if (gph == 25) asm volatile("s_waitcnt vmcnt(5)" ::: "memory");
      else if (gph == 26) asm volatile("s_waitcnt vmcnt(4)" ::: "memory");
      else if (gph == 27) asm volatile("s_waitcnt vmcnt(3)" ::: "memory");
      else if (gph == 28) asm volatile("s_waitcnt vmcnt(2)" ::: "memory");
      else if (gph == 29) asm volatile("s_waitcnt vmcnt(1)" ::: "memory");
      else if (gph == 30) asm volatile("s_waitcnt vmcnt(0)" ::: "memory");
      BARR;
      // ---- MFMA cluster
      __builtin_amdgcn_s_setprio(1);
#pragma unroll
      for (int ks = 0; ks < 2; ++ks)
#pragma unroll
        for (int m2 = 0; m2 < 2; ++m2)
#pragma unroll
          for (int ni = 0; ni < 4; ++ni)
            acc[q * 2 + m2][ni] = __builtin_amdgcn_mfma_f32_16x16x32_bf16(
                af[m2][ks], bfr[ni][ks], acc[q * 2 + m2][ni], 0, 0, 0);
      __builtin_amdgcn_s_setprio(0);
      BARR;
    }
  }

  // epilogue: C/D mapping col=lane&15, row=(lane>>4)*4+reg. Row-burst order.
  const int cr = (lane >> 4) * 4, cc = lane & 15;
  float bv[4], lsum[4], lsq[4];
#pragma unroll
  for (int ni = 0; ni < 4; ++ni) {
    bv[ni] = bias[n0 + wn * 64 + ni * 16 + cc];
    lsum[ni] = 0.f; lsq[ni] = 0.f;
  }
#pragma unroll
  for (int mi = 0; mi < 8; ++mi) {
#pragma unroll
    for (int jj = 0; jj < 4; ++jj) {
      const size_t row = (size_t)(m0 + wm * 128 + mi * 16 + cr + jj);
#pragma unroll
      for (int ni = 0; ni < 4; ++ni) {
        int col = n0 + wn * 64 + ni * 16 + cc;
        float v = acc[mi][ni][jj] + bv[ni];
        if (OUT_BF16) Cb[row * N + col] = f2bf(v);
        else          Cf[row * N + col] = v;
        if (STATS) { lsum[ni] += v; lsq[ni] += v * v; }
      }
    }
  }
  if (STATS) {
#pragma unroll
    for (int ni = 0; ni < 4; ++ni) {
      float s = lsum[ni], q = lsq[ni];
      s += __shfl_xor(s, 16); s += __shfl_xor(s, 32);
      q += __shfl_xor(q, 16); q += __shfl_xor(q, 32);
      if (lane < 16) {
        int col = n0 + wn * 64 + ni * 16 + lane;
        atomicAdd(&gstats[col], s);
        atomicAdd(&gstats[512 + col], q);
      }
    }
  }
}

// ------------------------------------------ finalize column stats from atomic sums
__global__ __launch_bounds__(512) void statsfin_kernel(const float* __restrict__ part,
                                                       float* __restrict__ stats, int off) {
  int t = threadIdx.x;
  float mean = part[t] / 32768.f;
  float var = part[512 + t] / 32768.f - mean * mean;
  stats[off + t] = mean;
  stats[off + 512 + t] = rsqrtf(var + 1e-5f);
}

// ---------------------------------------------------------------- MFMA attention
// One wave per (n,h). L=32, d=64. (R4: verified, 470us total.)
__global__ __launch_bounds__(64) void attn3_kernel(const unsigned short* __restrict__ qkv,
                                                   unsigned short* __restrict__ ctxb) {
  const int n = blockIdx.x, h = blockIdx.y;
  const int lane = threadIdx.x;
  const int fr = lane & 15, g = lane >> 4;
  const int r = lane & 31, hi2 = lane >> 5;
  __shared__ unsigned short vt[64 * 32];   // vt[d][m] = V[m][d]

  const unsigned short* base = qkv + (size_t)n * 1536 + (size_t)h * 64;

  // ---- V load (rows r, 16B chunks) + in-register pair-transpose -> vt
#pragma unroll
  for (int i = 0; i < 4; ++i) {
    const int d0 = (i * 2 + hi2) * 8;
    union { us8_t v; unsigned u[4]; } ov;
    ov.v = *(const us8_t*)(base + (size_t)r * 1572864 + 1024 + d0);
#pragma unroll
    for (int w = 0; w < 4; ++w) {
      unsigned o = ov.u[w];
      unsigned pu = __shfl_xor(o, 1);
      unsigned val = (r & 1) ? ((pu >> 16) | (o & 0xFFFF0000u))
                             : ((o & 0xFFFFu) | (pu << 16));
      int dw = d0 + 2 * w + (r & 1);
      *(unsigned*)&vt[dw * 32 + (r >> 1) * 2] = val;
    }
  }

  // ---- K/Q fragments direct from global (bf16, no staging)
  bf16x8_t kfr[2][2], qfr[2][2];
#pragma unroll
  for (int mi = 0; mi < 2; ++mi)
#pragma unroll
    for (int s = 0; s < 2; ++s)
      kfr[mi][s] = *(const bf16x8_t*)(base + (size_t)(mi * 16 + fr) * 1572864 + 512 + s * 32 + g * 8);
#pragma unroll
  for (int li = 0; li < 2; ++li)
#pragma unroll
    for (int s = 0; s < 2; ++s)
      qfr[li][s] = *(const bf16x8_t*)(base + (size_t)(li * 16 + fr) * 1572864 + s * 32 + g * 8);

  // ---- scores^T = K·Q^T
  f32x4_t st[2][2];
#pragma unroll
  for (int mi = 0; mi < 2; ++mi)
#pragma unroll
    for (int li = 0; li < 2; ++li) {
      st[mi][li] = (f32x4_t){0.f, 0.f, 0.f, 0.f};
#pragma unroll
      for (int s = 0; s < 2; ++s)
        st[mi][li] = __builtin_amdgcn_mfma_f32_16x16x32_bf16(kfr[mi][s], qfr[li][s], st[mi][li], 0, 0, 0);
    }

  __syncthreads();   // vt ready
  bf16x8_t vf[4];
#pragma unroll
  for (int dj = 0; dj < 4; ++dj)
    vf[dj] = *(const bf16x8_t*)&vt[(dj * 16 + fr) * 32 + g * 8];

  const bool pj = (g & 1) != 0, hb = (g >> 1) != 0;
  f32x4_t outacc[2][4];
#pragma unroll
  for (int li = 0; li < 2; ++li) {
    float mx = -3e38f;
#pragma unroll
    for (int mi = 0; mi < 2; ++mi)
#pragma unroll
      for (int rr = 0; rr < 4; ++rr) mx = fmaxf(mx, st[mi][li][rr]);
    mx = fmaxf(mx, __shfl_xor(mx, 16));
    mx = fmaxf(mx, __shfl_xor(mx, 32));
    float e[2][4]; float sm = 0.f;
#pragma unroll
    for (int mi = 0; mi < 2; ++mi)
#pragma unroll
      for (int rr = 0; rr < 4; ++rr) {
        float ev = __expf((st[mi][li][rr] - mx) * 0.125f);
        e[mi][rr] = ev; sm += ev;
      }
    sm += __shfl_xor(sm, 16);
    sm += __shfl_xor(sm, 32);
    float inv = 1.f / sm;
    unsigned ww00 = ((unsigned)f2bf(e[0][1] * inv) << 16) | f2bf(e[0][0] * inv);
    unsigned ww01 = ((unsigned)f2bf(e[0][3] * inv) << 16) | f2bf(e[0][2] * inv);
    unsigned ww10 = ((unsigned)f2bf(e[1][1] * inv) << 16) | f2bf(e[1][0] * inv);
    unsigned ww11 = ((unsigned)f2bf(e[1][3] * inv) << 16) | f2bf(e[1][2] * inv);
    unsigned pw00 = __shfl_xor(ww00, 16), pw01 = __shfl_xor(ww01, 16);
    unsigned pw10 = __shfl_xor(ww10, 16), pw11 = __shfl_xor(ww11, 16);
    unsigned s00 = pj ? (hb ? pw00 : pw10) : (hb ? ww00 : ww10);
    unsigned s01 = pj ? (hb ? pw01 : pw11) : (hb ? ww01 : ww11);
    unsigned s10 = pj ? (hb ? ww00 : ww10) : (hb ? pw00 : pw10);
    unsigned s11 = pj ? (hb ? ww01 : ww11) : (hb ? pw01 : pw11);
    unsigned sb00 = __shfl_xor(s00, 32), sb01 = __shfl_xor(s01, 32);
    unsigned sb10 = __shfl_xor(s10, 32), sb11 = __shfl_xor(s11, 32);
    unsigned k00 = pj ? (hb ? pw10 : pw00) : (hb ? ww10 : ww00);
    unsigned k01 = pj ? (hb ? pw11 : pw01) : (hb ? ww11 : ww01);
    unsigned k10 = pj ? (hb ? ww10 : ww00) : (hb ? pw10 : pw00);
    unsigned k11 = pj ? (hb ? ww11 : ww01) : (hb ? pw11 : pw01);
    const bool take = (pj != hb);
    union { unsigned u[4]; bf16x8_t v; } pa;
    pa.u[0] = take ? sb00 : k00;
    pa.u[1] = take ? sb01 : k01;
    pa.u[2] = take ? sb10 : k10;
    pa.u[3] = take ? sb11 : k11;
#pragma unroll
    for (int dj = 0; dj < 4; ++dj)
      outacc[li][dj] = __builtin_amdgcn_mfma_f32_16x16x32_bf16(
          pa.v, vf[dj], (f32x4_t){0.f, 0.f, 0.f, 0.f}, 0, 0, 0);
  }

#pragma unroll
  for (int li = 0; li < 2; ++li)
#pragma unroll
    for (int dj = 0; dj < 4; ++dj)
#pragma unroll
      for (int rr = 0; rr < 4; ++rr) {
        int l = li * 16 + g * 4 + rr;
        ctxb[((size_t)l * 1024 + n) * 512 + h * 64 + dj * 16 + fr] = f2bf(outacc[li][dj][rr]);
      }
}

// ---------------------------------------------------------------- projection (M x 8), fp32 x
__global__ __launch_bounds__(256) void proj_kernel(const float* __restrict__ x,
    const float* __restrict__ pw, const float* __restrict__ pb, float* __restrict__ p) {
  int blk = blockIdx.x, t = threadIdx.x;
  int r0 = blk * 64;
  __shared__ float xsp[64 * 33];
  __shared__ float pwc[8 * 33];
  int l = t >> 2, fg = t & 3;
  float acc0 = 0.f, acc1 = 0.f;
  for (int k0 = 0; k0 < 512; k0 += 32) {
    __syncthreads();
    for (int i = t; i < 2048; i += 256) { int ll = i >> 5, kk = i & 31; xsp[ll * 33 + kk] = x[(size_t)(r0 + ll) * 512 + k0 + kk]; }
    { int ff = t >> 5, kk = t & 31; pwc[ff * 33 + kk] = pw[ff * 512 + k0 + kk]; }
    __syncthreads();
#pragma unroll 8
    for (int kk = 0; kk < 32; ++kk) {
      float xv = xsp[l * 33 + kk];
      acc0 += xv * pwc[(fg * 2) * 33 + kk];
      acc1 += xv * pwc[(fg * 2 + 1) * 33 + kk];
    }
  }
  float2 o; o.x = acc0 + pb[fg * 2]; o.y = acc1 + pb[fg * 2 + 1];
  *(float2*)&p[(r0 + l) * 8 + fg * 2] = o;
}

// ---------------------------------------------------------------- proj BN stats (C=8)
__global__ __launch_bounds__(256) void projstats_kernel(const float* __restrict__ p,
                                                        float* __restrict__ part) {
  int t = threadIdx.x, blk = blockIdx.x;  // 64 blocks
  int f = t & 7;
  float s = 0.f, s2 = 0.f;
  for (int r = blk * 32 + (t >> 3); r < 32768; r += 2048) { float v = p[r * 8 + f]; s += v; s2 += v * v; }
  __shared__ float red[256], red2[256];
  red[t] = s; red2[t] = s2; __syncthreads();
  for (int off = 128; off >= 8; off >>= 1) { if (t < off) { red[t] += red[t + off]; red2[t] += red2[t + off]; } __syncthreads(); }
  if (t < 8) { part[blk * 16 + t] = red[t]; part[blk * 16 + 8 + t] = red2[t]; }
}
__global__ void projfin_kernel(const float* __restrict__ part, float* __restrict__ stats) {
  int t = threadIdx.x;
  if (t < 8) {
    float s = 0.f, s2 = 0.f;
    for (int b = 0; b < 64; ++b) { s += part[b * 16 + t]; s2 += part[b * 16 + 8 + t]; }
    float mean = s / 32768.f;
    float var = s2 / 32768.f - mean * mean;
    stats[SOFF_PMEAN + t] = mean;
    stats[SOFF_PRSTD + t] = rsqrtf(var + 1e-5f);
  }
}

// ------------------------------------------------- apply proj-BN in place + min/max
__global__ __launch_bounds__(256) void bnminmax_kernel(float* __restrict__ p,
    const float* __restrict__ stats, const float* __restrict__ png,
    const float* __restrict__ pnb, float* __restrict__ part) {
  int t = threadIdx.x, blk = blockIdx.x;  // 64 blocks
  int i0 = blk * 256 + t;
  int f = i0 & 7;
  float k1 = stats[SOFF_PRSTD + f] * png[f];
  float k0 = pnb[f] - stats[SOFF_PMEAN + f] * k1;
  float mn = 3e38f, mx = -3e38f;
  for (int i = i0; i < 262144; i += 16384) {
    float v = p[i] * k1 + k0;
    p[i] = v;
    mn = fminf(mn, v); mx = fmaxf(mx, v);
  }
  __shared__ float rmn[256], rmx[256];
  rmn[t] = mn; rmx[t] = mx; __syncthreads();
  for (int off = 128; off >= 8; off >>= 1) {
    if (t < off) { rmn[t] = fminf(rmn[t], rmn[t + off]); rmx[t] = fmaxf(rmx[t], rmx[t + off]); }
    __syncthreads();
  }
  if (t < 8) { part[blk * 16 + t] = rmn[t]; part[blk * 16 + 8 + t] = rmx[t]; }
}
__global__ void minmaxfin_kernel(const float* __restrict__ part, float* __restrict__ stats) {
  int t = threadIdx.x;
  if (t < 8) {
    float mn = 3e38f, mx = -3e38f;
    for (int b = 0; b < 64; ++b) { mn = fminf(mn, part[b * 16 + t]); mx = fmaxf(mx, part[b * 16 + 8 + t]); }
    stats[SOFF_FMIN + t] = mn;
    stats[SOFF_FMAX + t] = mx;
  }
}

// ---------------------------------------------------------------- spline (in place)
__global__ __launch_bounds__(256) void spline_kernel(float* __restrict__ p,
    const float* __restrict__ knots, const float* __restrict__ cps,
    const float* __restrict__ stats) {
  __shared__ float ksh[8 * 33], csh[8 * 33];
  int t = threadIdx.x;
  { int f = t >> 5, j = t & 31; ksh[f * 33 + j] = knots[t]; csh[f * 33 + j] = cps[t]; }
  __syncthreads();
  int i = blockIdx.x * 256 + t;
  int f = i & 7;
  float xv = p[i];
  float mn = stats[SOFF_FMIN + f], mx = stats[SOFF_FMAX + f];
  float xn = (xv - mn) / (mx - mn + 1e-6f);
  const float* kn = &ksh[f * 33];
  const float* cp = &csh[f * 33];
  int pcnt = 0;
#pragma unroll
  for (int j = 0; j < 32; ++j) pcnt += (kn[j] <= xn) ? 1 : 0;
  int idx = pcnt - 1;
  idx = idx < 0 ? 0 : (idx > 30 ? 30 : idx);
  float k0v = kn[idx], k1v = kn[idx + 1];
  float tt = (xn - k0v) / (k1v - k0v);
  float val = (1.f - tt) * cp[idx] + tt * cp[idx + 1];
  bool inr = (xn >= kn[0]) && (xn <= kn[31]);
  p[i] = inr ? val : 0.f;
}

// ------------------------------------------- gate-weight Grams (parallel, 88 blocks)
__global__ __launch_bounds__(256) void gateprep_kernel(const float* __restrict__ gw,
    const float* __restrict__ gb, float* __restrict__ stats) {
  int b = blockIdx.x, t = threadIdx.x;
  __shared__ float red[256];
  float s = 0.f;
  if (b < 64) {
    int f1 = b >> 3, f2 = b & 7;
    for (int j = t; j < 1024; j += 256) s += gw[j * 8 + f1] * gw[j * 8 + f2];
  } else if (b < 72) {
    int f = b - 64;
    for (int j = t; j < 1024; j += 256) s += gw[j * 8 + f];
  } else if (b < 80) {
    int f = b - 72;
    for (int j = t; j < 1024; j += 256) s += gb[j] * gw[j * 8 + f];
  } else if (b == 80) {
    for (int j = t; j < 1024; j += 256) s += gb[j];
  } else {
    for (int j = t; j < 1024; j += 256) s += gb[j] * gb[j];
  }
  red[t] = s; __syncthreads();
  for (int off = 128; off > 0; off >>= 1) { if (t < off) red[t] += red[t + off]; __syncthreads(); }
  if (t == 0) {
    float v = red[0];
    if (b < 64) stats[SOFF_G2 + b] = v;
    else if (b < 72) stats[SOFF_G1 + (b - 64)] = v;
    else if (b < 80) stats[SOFF_GB + (b - 72)] = v;
    else if (b == 80) stats[SOFF_SGB] = v;
    else stats[SOFF_QGB] = v;
  }
}

// -------------------------------------- per-s BN stats of h WITHOUT materializing h
__global__ __launch_bounds__(256) void sstats_kernel(const float* __restrict__ tbuf,
                                                     float* __restrict__ stats) {
  int s = blockIdx.x, t = threadIdx.x;
  __shared__ float tv[256];
  __shared__ float red[256];
  __shared__ float T1[8];
  __shared__ float Ms[64];
  int b = t >> 3, f = t & 7;
  tv[t] = tbuf[(b * 1024 + s) * 8 + f];
  __syncthreads();
  red[t] = tv[t]; __syncthreads();
  for (int off = 128; off >= 8; off >>= 1) { if (t < off) red[t] += red[t + off]; __syncthreads(); }
  if (t < 8) T1[t] = red[t];
  if (t < 64) {
    int f1 = t >> 3, f2 = t & 7; float sM = 0.f;
    for (int bb = 0; bb < 32; ++bb) sM += tv[bb * 8 + f1] * tv[bb * 8 + f2];
    Ms[t] = sM;
  }
  __syncthreads();
  if (t == 0) {
    float sh = 0.f, s2 = 0.f;
    for (int ff = 0; ff < 8; ++ff) {
      sh += stats[SOFF_G1 + ff] * T1[ff];
      s2 += 2.f * stats[SOFF_GB + ff] * T1[ff];
    }
    sh += 32.f * stats[SOFF_SGB];
    for (int i = 0; i < 64; ++i) s2 += Ms[i] * stats[SOFF_G2 + i];
    s2 += 32.f * stats[SOFF_QGB];
    float mean = sh / 32768.f;
    float var = s2 / 32768.f - mean * mean;
    stats[SOFF_SMEAN + s] = mean;
    stats[SOFF_SRSTD + s] = rsqrtf(var + 1e-5f);
  }
}

// ---- recompute h row (fp32 gate_w — MUST match sstats' weights), BN-s, GLU, LN
__global__ __launch_bounds__(256) void gluln_kernel(const float* __restrict__ tbuf,
    const float* __restrict__ gw, const float* __restrict__ gb,
    const float* __restrict__ stats, const float* __restrict__ gbng,
    const float* __restrict__ gbnb, const float* __restrict__ lng,
    const float* __restrict__ lnb, unsigned short* __restrict__ gatedb) {
  const int t = threadIdx.x, wave = t >> 6, lane = t & 63;
  for (int rr = 0; rr < 4; ++rr) {
    const int r = blockIdx.x * 16 + wave * 4 + rr;
    const int s = r & 1023;
    float4 tA = *(const float4*)&tbuf[r * 8];
    float4 tB = *(const float4*)&tbuf[r * 8 + 4];
    float smean = stats[SOFF_SMEAN + s], srstd = stats[SOFF_SRSTD + s];
    float k1 = srstd * gbng[s];
    float k0 = gbnb[s] - smean * k1;
    float g[8];
    float sum = 0.f, sq = 0.f;
#pragma unroll
    for (int i = 0; i < 8; ++i) {
      int c = i * 64 + lane;
      float4 wa0 = *(const float4*)&gw[c * 8];
      float4 wa1 = *(const float4*)&gw[c * 8 + 4];
      float4 wb0 = *(const float4*)&gw[(c + 512) * 8];
      float4 wb1 = *(const float4*)&gw[(c + 512) * 8 + 4];
      float ha = tA.x * wa0.x + tA.y * wa0.y + tA.z * wa0.z + tA.w * wa0.w
               + tB.x * wa1.x + tB.y * wa1.y + tB.z * wa1.z + tB.w * wa1.w + gb[c];
      float hb = tA.x * wb0.x + tA.y * wb0.y + tA.z * wb0.z + tA.w * wb0.w
               + tB.x * wb1.x + tB.y * wb1.y + tB.z * wb1.z + tB.w * wb1.w + gb[c + 512];
      ha = ha * k1 + k0;
      hb = hb * k1 + k0;
      float gv = ha / (1.f + __expf(-hb));
      g[i] = gv; sum += gv; sq += gv * gv;
    }
#pragma unroll
    for (int m = 32; m >= 1; m >>= 1) { sum += __shfl_xor(sum, m); sq += __shfl_xor(sq, m); }
    float mean = sum * (1.f / 512.f);
    float rstd = rsqrtf(sq * (1.f / 512.f) - mean * mean + 1e-5f);
#pragma unroll
    for (int i = 0; i < 8; ++i) {
      int c = i * 64 + lane;
      gatedb[(size_t)r * 512 + c] = f2bf((g[i] - mean) * rstd * lng[c] + lnb[c]);
    }
  }
}

// ---------------------------------------------------------------- final elementwise
__global__ __launch_bounds__(256) void final_kernel(const float* __restrict__ x,
    const float* __restrict__ attn, const float* __restrict__ outl,
    const float* __restrict__ stats, const float* __restrict__ ag,
    const float* __restrict__ ab, const float* __restrict__ og,
    const float* __restrict__ ob, float* __restrict__ y) {
  int idx = blockIdx.x * 256 + threadIdx.x;
  int c4 = (idx & 127) * 4;
  float4 xv = ((const float4*)x)[idx];
  float4 av = ((const float4*)attn)[idx];
  float4 ov = ((const float4*)outl)[idx];
  float4 am = *(const float4*)&stats[SOFF_AMEAN + c4];
  float4 ar = *(const float4*)&stats[SOFF_ARSTD + c4];
  float4 om = *(const float4*)&stats[SOFF_OMEAN + c4];
  float4 orr = *(const float4*)&stats[SOFF_ORSTD + c4];
  float4 g1 = *(const float4*)&ag[c4];
  float4 b1 = *(const float4*)&ab[c4];
  float4 g2 = *(const float4*)&og[c4];
  float4 b2 = *(const float4*)&ob[c4];
  float4 o;
  o.x = xv.x + (av.x - am.x) * ar.x * g1.x + b1.x + (ov.x - om.x) * orr.x * g2.x + b2.x;
  o.y = xv.y + (av.y - am.y) * ar.y * g1.y + b1.y + (ov.y - om.y) * orr.y * g2.y + b2.y;
  o.z = xv.z + (av.z - am.z) * ar.z * g1.z + b1.z + (ov.z - om.z) * orr.z * g2.z + b2.z;
  o.w = xv.w + (av.w - am.w) * ar.w * g1.w + b1.w + (ov.w - om.w) * orr.w * g2.w + b2.w;
  ((float4*)y)[idx] = o;
}

extern "C" void kernel_launch(void* const* d_in, const int* in_sizes, int n_in,
                              void* d_out, int out_size, void* d_ws, size_t ws_size,
                              hipStream_t stream) {
  (void)in_sizes; (void)n_in; (void)out_size; (void)ws_size;
  const float* x        = (const float*)d_in[0];
  const float* in_w     = (const float*)d_in[1];
  const float* in_b     = (const float*)d_in[2];
  const float* out_w    = (const float*)d_in[3];
  const float* out_b    = (const float*)d_in[4];
  const float* attn_g   = (const float*)d_in[5];
  const float* attn_bt  = (const float*)d_in[6];
  const float* proj_w   = (const float*)d_in[7];
  const float* proj_b   = (const float*)d_in[8];
  const float* pn_g     = (const float*)d_in[9];
  const float* pn_bt    = (const float*)d_in[10];
  const float* knots    = (const float*)d_in[11];
  const float* cps      = (const float*)d_in[12];
  const float* gate_w   = (const float*)d_in[13];
  const float* gate_b   = (const float*)d_in[14];
  const float* gbn_g    = (const float*)d_in[15];
  const float* gbn_bt   = (const float*)d_in[16];
  const float* ln_g     = (const float*)d_in[17];
  const float* ln_bt    = (const float*)d_in[18];
  const float* outp_w   = (const float*)d_in[19];
  const float* outp_b   = (const float*)d_in[20];
  const float* on_g     = (const float*)d_in[21];
  const float* on_bt    = (const float*)d_in[22];

  float* out = (float*)d_out;
  unsigned short* xb      = (unsigned short*)d_ws;      // 16777216
  unsigned short* qkv_b   = xb + 16777216;              // 50331648
  unsigned short* ctx_b   = qkv_b + 50331648;           // 16777216
  unsigned short* wqkv_b  = ctx_b + 16777216;           // 786432
  unsigned short* wout_b  = wqkv_b + 786432;            // 262144
  unsigned short* woutp_b = wout_b + 262144;            // 262144
  float* proj  = (float*)(woutp_b + 262144);            // 262144 floats
  float* stats = proj + 262144;
  float* part  = stats + SOFF_PART;                     // 4096 floats
  float* partA  = part;                                 // 1024 (atomic col stats attn)
  float* partO  = part + 1024;                          // 1024 (atomic col stats out)
  float* partP  = part + 2048;                          // 1024 (projstats partials)
  float* partMM = part + 3072;                          // 1024 (minmax partials)
  float* attnf = (float*)qkv_b;      // alias: qkv dead after attn3
  unsigned short* gated_b = xb;      // alias: xb dead after qkv GEMM

  zero_kernel<<<dim3(8), dim3(256), 0, stream>>>(part);   // partA+partO
  cvt8_kernel<<<dim3(8192), dim3(256), 0, stream>>>(x, xb);
  cvt8_kernel<<<dim3(384), dim3(256), 0, stream>>>(in_w, wqkv_b);
  cvt8_kernel<<<dim3(128), dim3(256), 0, stream>>>(out_w, wout_b);
  cvt8_kernel<<<dim3(128), dim3(256), 0, stream>>>(outp_w, woutp_b);
  // qkv = x @ in_w^T + in_b -> bf16   (128 m-tiles x 6 n-tiles = 768 blocks)
  gemm256_kernel<6, true, false><<<dim3(768), dim3(512), 0, stream>>>(
      xb, wqkv_b, in_b, qkv_b, nullptr, nullptr, 1536);
  attn3_kernel<<<dim3(1024, 8), dim3(64), 0, stream>>>(qkv_b, ctx_b);
  // attn_lin = ctx @ out_w^T + out_b -> fp32 (+ fused column stats)
  gemm256_kernel<2, false, true><<<dim3(256), dim3(512), 0, stream>>>(
      ctx_b, wout_b, out_b, nullptr, attnf, partA, 512);
  statsfin_kernel<<<dim3(1), dim3(512), 0, stream>>>(partA, stats, SOFF_AMEAN);
  proj_kernel<<<dim3(512), dim3(256), 0, stream>>>(x, proj_w, proj_b, proj);
  projstats_kernel<<<dim3(64), dim3(256), 0, stream>>>(proj, partP);
  projfin_kernel<<<dim3(1), dim3(64), 0, stream>>>(partP, stats);
  bnminmax_kernel<<<dim3(64), dim3(256), 0, stream>>>(proj, stats, pn_g, pn_bt, partMM);
  minmaxfin_kernel<<<dim3(1), dim3(64), 0, stream>>>(partMM, stats);
  spline_kernel<<<dim3(1024), dim3(256), 0, stream>>>(proj, knots, cps, stats);
  gateprep_kernel<<<dim3(88), dim3(256), 0, stream>>>(gate_w, gate_b, stats);
  sstats_kernel<<<dim3(1024), dim3(256), 0, stream>>>(proj, stats);
  gluln_kernel<<<dim3(2048), dim3(256), 0, stream>>>(proj, gate_w, gate_b, stats,
                                                     gbn_g, gbn_bt, ln_g, ln_bt, gated_b);
  // out = gated @ outp_w^T + outp_b -> fp32 (+ fused column stats)
  gemm256_kernel<2, false, true><<<dim3(256), dim3(512), 0, stream>>>(
      gated_b, woutp_b, outp_b, nullptr, out, partO, 512);
  statsfin_kernel<<<dim3(1), dim3(512), 0, stream>>>(partO, stats, SOFF_OMEAN);
  final_kernel<<<dim3(16384), dim3(256), 0, stream>>>(x, attnf, out, stats,
                                                      attn_g, attn_bt, on_g, on_bt, out);
}